// Round 4
// baseline (174.910 us; speedup 1.0000x reference)
//
#include <hip/hip_runtime.h>
#include <hip/hip_bf16.h>
#include <stdint.h>

// out[4096,4096] = x[4096,2048] @ matrix[0,4096,2048]^T   (fp32 in/out)
// R4: cast pass unchanged. GEMM: block tile 256x128 (4 waves x 128x64 as 8x4
// frags of 16x16x32), BK=32, DOUBLE-BUFFERED LDS: DMA for tile k+1 issued
// before compute of tile k, so the vmcnt(0) drain at __syncthreads overlaps
// the MFMA stretch (R3 was drain-bound: 45% of cycles no pipe busy).
// LDS layout: packed-pair lines -- line = m>>1 (128B), slot = (m&1)*4 +
// (chunk ^ (line&3)); full 32-bank coverage, 2-way alias only (free).

#define GAS __attribute__((address_space(1)))
#define LAS __attribute__((address_space(3)))

typedef __bf16 bf16x8 __attribute__((ext_vector_type(8)));
typedef float f32x4 __attribute__((ext_vector_type(4)));

static __device__ __forceinline__ unsigned short f2bf(float f) {
  union { float f; uint32_t u; } a; a.f = f;
  uint32_t u = a.u;
  u += 0x7FFFu + ((u >> 16) & 1u);   // round-to-nearest-even
  return (unsigned short)(u >> 16);
}

__global__ void cvt_f32_to_bf16(const float4* __restrict__ x,
                                const float4* __restrict__ m,
                                ushort4* __restrict__ xo,
                                ushort4* __restrict__ mo) {
  const int i = blockIdx.x * blockDim.x + threadIdx.x;
  const float4* __restrict__ src = blockIdx.y ? m : x;
  ushort4* __restrict__ dst      = blockIdx.y ? mo : xo;
  float4 v = src[i];
  ushort4 o;
  o.x = f2bf(v.x); o.y = f2bf(v.y); o.z = f2bf(v.z); o.w = f2bf(v.w);
  dst[i] = o;
}

// C[M,N] = A[M,K]*B[N,K]^T, M=N=4096, K=2048. 256 threads = 4 waves.
// Per buffer: A = 256 rows x 32 k = 8192 elems (16KB), B = 128 x 32 = 4096
// elems (8KB). Two buffers: 48KB total -> 2 blocks/CU.
__global__ __launch_bounds__(256, 2)
void gemm_bt_bf16(const unsigned short* __restrict__ A,
                  const unsigned short* __restrict__ B,
                  float* __restrict__ C) {
  constexpr int K = 2048;
  constexpr int N = 4096;
  constexpr int BUF = 12288;   // elems per buffer (A 8192 + B 4096)

  __shared__ unsigned short L[2 * BUF];   // 48 KB

  const int tid  = threadIdx.x;
  const int wave = tid >> 6;
  const int lane = tid & 63;
  const int wm   = wave & 1;
  const int wn   = wave >> 1;
  const int bM   = blockIdx.y * 256;
  const int bN   = blockIdx.x * 128;

  const int quad = lane >> 4;   // 0..3 == k-chunk of the fragment (BK=32)
  const int l15  = lane & 15;

  // ---- staging lane map (per 1KB DMA inst = 8 lines = 16 rows) ----
  // lane covers line (lane>>3), slot (lane&7) -> row-in-inst r0 = 2*(lane>>3)
  // + ((lane&7)>>2), global k-chunk c = (lane&3) ^ ((lane>>3)&3).
  const int r0 = 2 * (lane >> 3) + ((lane & 7) >> 2);
  const int c  = (lane & 3) ^ ((lane >> 3) & 3);
  // A: wave stages rows [wave*64, +64) in 4 insts of 16 rows.
  // B: wave stages rows [wave*32, +32) in 2 insts.
  const size_t aBase = (size_t)(bM + wave * 64 + r0) * K + c * 8;
  const size_t bBase = (size_t)(bN + wave * 32 + r0) * K + c * 8;
  unsigned short* const aDst = L + wave * 2048;          // + buf*BUF + t*512
  unsigned short* const bDst = L + 8192 + wave * 1024;   // + buf*BUF + t*512

  // ---- fragment LDS offsets (elems), constant per lane; +512 per i ----
  const int lineA0 = wm * 64 + (l15 >> 1);
  const int aOff0  = lineA0 * 64 + ((l15 & 1) * 4 + (quad ^ (lineA0 & 3))) * 8;
  const int lineB0 = wn * 32 + (l15 >> 1);
  const int bOff0  = 8192 + lineB0 * 64 + ((l15 & 1) * 4 + (quad ^ (lineB0 & 3))) * 8;

  f32x4 acc[8][4] = {};

#define STAGE(k0, buf)                                                         \
  {                                                                            \
    _Pragma("unroll")                                                          \
    for (int t = 0; t < 4; ++t)                                                \
      __builtin_amdgcn_global_load_lds(                                        \
          (const GAS void*)(A + aBase + (k0) + (size_t)t * 16 * K),            \
          (LAS void*)(aDst + (buf) * BUF + t * 512), 16, 0, 0);                \
    _Pragma("unroll")                                                          \
    for (int t = 0; t < 2; ++t)                                                \
      __builtin_amdgcn_global_load_lds(                                        \
          (const GAS void*)(B + bBase + (k0) + (size_t)t * 16 * K),            \
          (LAS void*)(bDst + (buf) * BUF + t * 512), 16, 0, 0);                \
  }

#define COMPUTE(buf)                                                           \
  {                                                                            \
    bf16x8 af[8], bfr[4];                                                      \
    _Pragma("unroll")                                                          \
    for (int i = 0; i < 8; ++i)                                                \
      af[i] = *(const bf16x8*)(L + (buf) * BUF + aOff0 + i * 512);             \
    _Pragma("unroll")                                                          \
    for (int j = 0; j < 4; ++j)                                                \
      bfr[j] = *(const bf16x8*)(L + (buf) * BUF + bOff0 + j * 512);            \
    _Pragma("unroll")                                                          \
    for (int i = 0; i < 8; ++i)                                                \
      _Pragma("unroll")                                                        \
      for (int j = 0; j < 4; ++j)                                              \
        acc[i][j] = __builtin_amdgcn_mfma_f32_16x16x32_bf16(af[i], bfr[j],     \
                                                            acc[i][j], 0, 0, 0); \
  }

  STAGE(0, 0);
  __syncthreads();

  for (int k0 = 0; k0 < K; k0 += 64) {
    // even half: compute chunk [k0, k0+32) from buf0, prefetch k0+32 -> buf1
    STAGE(k0 + 32, 1);            // k0+32 <= 2016 < K always
    COMPUTE(0);
    __syncthreads();
    // odd half: compute [k0+32, k0+64) from buf1, prefetch k0+64 -> buf0
    if (k0 + 64 < K) STAGE(k0 + 64, 0);
    COMPUTE(1);
    __syncthreads();
  }

#undef STAGE
#undef COMPUTE

  // Epilogue: C/D layout col=lane&15, row=quad*4+reg (m89-verified).
#pragma unroll
  for (int i = 0; i < 8; ++i) {
    const int row0 = bM + wm * 128 + i * 16 + quad * 4;
#pragma unroll
    for (int j = 0; j < 4; ++j) {
      const int col = bN + wn * 64 + j * 16 + l15;
#pragma unroll
      for (int t = 0; t < 4; ++t)
        C[(size_t)(row0 + t) * N + col] = acc[i][j][t];
    }
  }
}

extern "C" void kernel_launch(void* const* d_in, const int* in_sizes, int n_in,
                              void* d_out, int out_size, void* d_ws, size_t ws_size,
                              hipStream_t stream) {
  const float* x   = (const float*)d_in[0];   // [4096, 2048]
  const float* mat = (const float*)d_in[1];   // [1, 4096, 2048]
  float* out = (float*)d_out;                 // [4096, 4096]

  constexpr size_t ELEMS = 4096ull * 2048ull;
  unsigned short* xb = (unsigned short*)d_ws;
  unsigned short* mb = xb + ELEMS;

  dim3 cgrid((unsigned)(ELEMS / 4 / 256), 2);
  cvt_f32_to_bf16<<<cgrid, 256, 0, stream>>>((const float4*)x, (const float4*)mat,
                                             (ushort4*)xb, (ushort4*)mb);

  // 512 blocks: grid.x = N/128 = 32, grid.y = M/256 = 16 -> 2 blocks/CU
  gemm_bt_bf16<<<dim3(32, 16), 256, 0, stream>>>(xb, mb, out);
}